// Round 7
// baseline (268.903 us; speedup 1.0000x reference)
//
#include <hip/hip_runtime.h>

typedef __attribute__((ext_vector_type(8))) __bf16 bf16x8;
typedef __attribute__((ext_vector_type(4))) float f32x4;
typedef __attribute__((ext_vector_type(8))) unsigned short us8;
typedef __attribute__((ext_vector_type(4))) unsigned short us4;

#define NTOK 98
#define CDIM 192
#define NH 6
#define NWIN 64
#define BWIN 512
#define MROWS (BWIN * NTOK)     // 50176
#define NN (NTOK * NTOK)        // 9604
#define SCALE 0.17677669529663687f

#define PREP_BM (NWIN * NH * NN)   // 3687936
#define PREP_WQ (3 * CDIM * CDIM)  // 110592
#define PREP_WO (CDIM * CDIM)      // 36864
#define PREP_TOT (PREP_BM + PREP_WQ + PREP_WO)

// k_fused LDS map (bytes). Total 161824 <= 163840.
#define OFF_AS 0        // As: 98 x 200 x 2 = 39200 ; phase2 overlay: P, 7 x [16][136] x 2 = 30464
#define OFF_W  39200    // W tile: 64 x 200 x 2 = 25600 ; Q-scratch overlay: per wave 16 x 40 x 2
#define OFF_K  64800    // K: 6 heads x [112 tok][40] x 2 = 53760
#define OFF_VT 118560   // V^T: 6 heads x [32 d][112 tok] x 2 = 43008 + 256 zero pad
#define LDS_TOT 161824

__device__ __forceinline__ unsigned short f2b(float f) {
  unsigned u = __builtin_bit_cast(unsigned, f);
  u += 0x7FFFu + ((u >> 16) & 1u);   // RNE; inputs finite
  return (unsigned short)(u >> 16);
}

__device__ __forceinline__ bf16x8 ldfrag(const unsigned short* p) {
  return __builtin_bit_cast(bf16x8, *(const us8*)p);
}

// ---------------- K0: prep — bm[w][h][i][j] = table[relidx[ij]*6+h] + mask[w][ij] (fp32, exact
// for unmasked pairs since mask==0.0); wqb/wob = bf16(qkv_w / out_w)
__global__ __launch_bounds__(256) void k_prep(
    const float* __restrict__ table, const int* __restrict__ relidx,
    const float* __restrict__ mask, const float* __restrict__ wq,
    const float* __restrict__ wo, float* __restrict__ bm,
    unsigned short* __restrict__ wqb, unsigned short* __restrict__ wob) {
  int idx = blockIdx.x * 256 + threadIdx.x;
  if (idx < PREP_BM) {
    int w = idx / (NH * NN);
    int r = idx - w * NH * NN;
    int h = r / NN, ij = r - h * NN;
    bm[idx] = table[relidx[ij] * NH + h] + mask[w * NN + ij];
    return;
  }
  int i2 = idx - PREP_BM;
  if (i2 < PREP_WQ) { wqb[i2] = f2b(wq[i2]); return; }
  int i3 = i2 - PREP_WQ;
  if (i3 < PREP_TOT - PREP_BM - PREP_WQ) wob[i3] = f2b(wo[i3]);
}

// ---------------- K1: fused qkv-projection + attention. One block per window b.
// 7 waves; wave wv owns token rows [wv*16, wv*16+16).
__global__ __launch_bounds__(448, 2) void k_fused(
    const float* __restrict__ x, const unsigned short* __restrict__ wqb,
    const float* __restrict__ qkv_b, const float* __restrict__ bm,
    unsigned short* __restrict__ ao) {
  extern __shared__ char smem[];
  unsigned short* As = (unsigned short*)(smem + OFF_AS);
  unsigned short* Ws = (unsigned short*)(smem + OFF_W);
  unsigned short* Ks = (unsigned short*)(smem + OFF_K);
  unsigned short* Vt = (unsigned short*)(smem + OFF_VT);
  const int tid = threadIdx.x;
  const int b = blockIdx.x;
  const int lane = tid & 63, wv = tid >> 6;
  const int l15 = lane & 15, hi = lane >> 4;
  unsigned short* scr = Ws + wv * 640;          // per-wave 16x40 Q-transpose scratch (W overlay)

  // ---- stage x: 98x192 fp32 -> bf16, stride 200 (rows 98..111 of As stay garbage;
  //      all downstream consumers of those rows are masked/zero-weighted)
  for (int it = 0; it < 11; ++it) {
    int q = it * 448 + tid;
    if (q < 98 * 48) {
      int row = q / 48, c4 = q - row * 48;
      float4 v = *(const float4*)(x + ((size_t)b * NTOK + row) * CDIM + c4 * 4);
      us4 u = {f2b(v.x), f2b(v.y), f2b(v.z), f2b(v.w)};
      *(us4*)&As[row * 200 + c4 * 4] = u;
    }
  }

#define STAGEW(J)                                                              \
  for (int it = 0; it < 4; ++it) {                                             \
    int q = it * 448 + tid;                                                    \
    if (q < 1536) {                                                            \
      int row = q / 24, c8 = q - row * 24;                                     \
      *(us8*)&Ws[row * 200 + c8 * 8] =                                         \
          *(const us8*)(wqb + ((J) * 64 + row) * CDIM + c8 * 8);               \
    }                                                                          \
  }

#define DOMFMA(ACC)                                                            \
  _Pragma("unroll") for (int ks = 0; ks < 6; ++ks) {                           \
    int k0 = ks * 32 + hi * 8;                                                 \
    bf16x8 a = ldfrag(&As[(wv * 16 + l15) * 200 + k0]);                        \
    _Pragma("unroll") for (int fc = 0; fc < 4; ++fc) {                         \
      bf16x8 bw = ldfrag(&Ws[(fc * 16 + l15) * 200 + k0]);                     \
      ACC[fc] = __builtin_amdgcn_mfma_f32_16x16x32_bf16(a, bw, ACC[fc], 0, 0, 0); \
    }                                                                          \
  }

  bf16x8 qregs[6];
  // ---- Q tiles j=0..2 (unrolled: qregs index must be compile-time; rule #20)
#pragma unroll
  for (int j = 0; j < 3; ++j) {
    __syncthreads();                       // As ready / W+scratch free
    STAGEW(j);
    __syncthreads();                       // W ready
    f32x4 acc[4];
#pragma unroll
    for (int fc = 0; fc < 4; ++fc) acc[fc] = (f32x4)0.f;
    DOMFMA(acc);
    __syncthreads();                       // W dead -> scratch overlay safe
#pragma unroll
    for (int hh = 0; hh < 2; ++hh) {
#pragma unroll
      for (int fc2 = 0; fc2 < 2; ++fc2) {
        int fc = hh * 2 + fc2;
        float bia = qkv_b[j * 64 + fc * 16 + l15];
#pragma unroll
        for (int r = 0; r < 4; ++r)
          scr[(hi * 4 + r) * 40 + fc2 * 16 + l15] = f2b((acc[fc][r] + bia) * SCALE);
      }
      qregs[2 * j + hh] = ldfrag(&scr[l15 * 40 + hi * 8]);  // wave-local, in-order
    }
  }
  // ---- K tiles j=3..5, V tiles j=6..8
  for (int j = 3; j < 9; ++j) {
    __syncthreads();
    STAGEW(j);
    __syncthreads();
    f32x4 acc[4];
#pragma unroll
    for (int fc = 0; fc < 4; ++fc) acc[fc] = (f32x4)0.f;
    DOMFMA(acc);
    __syncthreads();
    if (j < 6) {                            // K -> Ks[head][token][40]
#pragma unroll
      for (int fc = 0; fc < 4; ++fc) {
        int c = j * 64 + fc * 16 + l15;
        int ci = c - CDIM, head = ci >> 5, d = ci & 31;
        float bia = qkv_b[c];
#pragma unroll
        for (int r = 0; r < 4; ++r)
          Ks[head * 4480 + (wv * 16 + hi * 4 + r) * 40 + d] = f2b(acc[fc][r] + bia);
      }
    } else {                                // V -> Vt[head][d][token] (us4 of 4 tokens)
#pragma unroll
      for (int fc = 0; fc < 4; ++fc) {
        int c = j * 64 + fc * 16 + l15;
        int ci = c - 2 * CDIM, head = ci >> 5, d = ci & 31;
        float bia = qkv_b[c];
        us4 u = {f2b(acc[fc][0] + bia), f2b(acc[fc][1] + bia),
                 f2b(acc[fc][2] + bia), f2b(acc[fc][3] + bia)};
        *(us4*)&Vt[head * 3584 + d * 112 + wv * 16 + hi * 4] = u;
      }
    }
  }
  __syncthreads();                          // K/V/Q complete; As dead
  // ---- zero V tokens [98,112) (garbage->NaN hazard under P=0 weights) + 256B pad;
  //      zero P cols [112,128) once (head loop only writes cols < 112)
  for (int i = tid; i < NH * 32 * 16; i += 448) {
    int hd = i >> 4, tk = 98 + (i & 15);
    if (tk < 112) Vt[hd * 112 + tk] = 0;
  }
  if (tid < 64) *(unsigned*)((char*)Vt + 43008 + tid * 4) = 0u;
  unsigned short* Pw = As + wv * 2176;      // per-wave [16][136] P tile (As overlay)
  *(us4*)&Pw[(lane >> 2) * 136 + 112 + (lane & 3) * 4] = (us4)(unsigned short)0;
  __syncthreads();

  // ---- phase 2: attention per head (no barriers; all cross-wave data read-only)
  const int wnd = b & (NWIN - 1);
#pragma unroll
  for (int h = 0; h < NH; ++h) {
    const unsigned short* Kh = Ks + h * 4480;
    const unsigned short* Vh = Vt + h * 3584;
    bf16x8 qf = qregs[h];
    f32x4 sacc[7];
#pragma unroll
    for (int tc = 0; tc < 7; ++tc) {
      bf16x8 kb = ldfrag(&Kh[(tc * 16 + l15) * 40 + hi * 8]);
      sacc[tc] = __builtin_amdgcn_mfma_f32_16x16x32_bf16(qf, kb, (f32x4)0.f, 0, 0, 0);
    }
    const float* bmp = bm + (size_t)(wnd * NH + h) * NN;
    float rsum[4];
#pragma unroll
    for (int r = 0; r < 4; ++r) {
      int row = wv * 16 + hi * 4 + r;
      float sv[7];
      float m = -1e30f;
#pragma unroll
      for (int tc = 0; tc < 7; ++tc) {
        int col = tc * 16 + l15;
        float val = -1e30f;
        if (col < NTOK && row < NTOK) val = sacc[tc][r] + bmp[row * NTOK + col];
        sv[tc] = val;
        m = fmaxf(m, val);
      }
#pragma unroll
      for (int off = 1; off < 16; off <<= 1) m = fmaxf(m, __shfl_xor(m, off));
      float s = 0.f;
#pragma unroll
      for (int tc = 0; tc < 7; ++tc) {
        float e = __expf(sv[tc] - m);
        s += e;
        Pw[(hi * 4 + r) * 136 + tc * 16 + l15] = f2b(e);
      }
#pragma unroll
      for (int off = 1; off < 16; off <<= 1) s += __shfl_xor(s, off);
      rsum[r] = s;
    }
    f32x4 oacc[2];
    oacc[0] = (f32x4)0.f; oacc[1] = (f32x4)0.f;
#pragma unroll
    for (int ks = 0; ks < 4; ++ks) {
      int k0 = ks * 32 + hi * 8;
      bf16x8 pa = ldfrag(&Pw[l15 * 136 + k0]);
#pragma unroll
      for (int tc2 = 0; tc2 < 2; ++tc2) {
        bf16x8 vb = ldfrag(&Vh[(tc2 * 16 + l15) * 112 + k0]);
        oacc[tc2] = __builtin_amdgcn_mfma_f32_16x16x32_bf16(pa, vb, oacc[tc2], 0, 0, 0);
      }
    }
#pragma unroll
    for (int tc2 = 0; tc2 < 2; ++tc2)
#pragma unroll
      for (int r = 0; r < 4; ++r) {
        int row = wv * 16 + hi * 4 + r;
        if (row < NTOK)
          ao[((size_t)b * NTOK + row) * CDIM + h * 32 + tc2 * 16 + l15] =
              f2b(oacc[tc2][r] / rsum[r]);
      }
  }
#undef STAGEW
#undef DOMFMA
}

// ---------------- K2: out = ao @ out_w^T + out_b (fp32 out)
__global__ __launch_bounds__(256) void k_proj(
    const unsigned short* __restrict__ a, const unsigned short* __restrict__ wob,
    const float* __restrict__ bias, float* __restrict__ out) {
  __shared__ unsigned short As[128 * 200];
  __shared__ unsigned short Bs[64 * 200];
  const int tid = threadIdx.x;
  const int m0 = blockIdx.x * 128;
  for (int it = 0; it < 12; ++it) {
    int q = it * 256 + tid;
    int row = q / 24, c8 = q - row * 24;
    *(us8*)&As[row * 200 + c8 * 8] = *(const us8*)(a + (m0 + row) * CDIM + c8 * 8);
  }
  const int lane = tid & 63;
  const int l15 = lane & 15, hi = lane >> 4;
  const int wr = (tid >> 6) >> 1, wc = (tid >> 6) & 1;
  __syncthreads();
  for (int j = 0; j < 3; ++j) {
    for (int it = 0; it < 6; ++it) {
      int q = it * 256 + tid;
      int row = q / 24, c8 = q - row * 24;
      *(us8*)&Bs[row * 200 + c8 * 8] = *(const us8*)(wob + (j * 64 + row) * CDIM + c8 * 8);
    }
    __syncthreads();
    f32x4 acc[4][2];
#pragma unroll
    for (int fr = 0; fr < 4; ++fr) { acc[fr][0] = (f32x4)0.f; acc[fr][1] = (f32x4)0.f; }
#pragma unroll
    for (int ks = 0; ks < 6; ++ks) {
      int k0 = ks * 32 + hi * 8;
      bf16x8 b0 = ldfrag(&Bs[(wc * 32 + l15) * 200 + k0]);
      bf16x8 b1 = ldfrag(&Bs[(wc * 32 + 16 + l15) * 200 + k0]);
#pragma unroll
      for (int fr = 0; fr < 4; ++fr) {
        bf16x8 aa = ldfrag(&As[(wr * 64 + fr * 16 + l15) * 200 + k0]);
        acc[fr][0] = __builtin_amdgcn_mfma_f32_16x16x32_bf16(aa, b0, acc[fr][0], 0, 0, 0);
        acc[fr][1] = __builtin_amdgcn_mfma_f32_16x16x32_bf16(aa, b1, acc[fr][1], 0, 0, 0);
      }
    }
    __syncthreads();
#pragma unroll
    for (int fr = 0; fr < 4; ++fr)
#pragma unroll
      for (int fc = 0; fc < 2; ++fc)
#pragma unroll
        for (int r = 0; r < 4; ++r) {
          int row = m0 + wr * 64 + fr * 16 + hi * 4 + r;
          int col = j * 64 + wc * 32 + fc * 16 + l15;
          out[row * CDIM + col] = acc[fr][fc][r] + bias[col];
        }
  }
}

extern "C" void kernel_launch(void* const* d_in, const int* in_sizes, int n_in,
                              void* d_out, int out_size, void* d_ws, size_t ws_size,
                              hipStream_t stream) {
  const float* x      = (const float*)d_in[0];
  const float* mask   = (const float*)d_in[1];
  const float* qkv_w  = (const float*)d_in[2];
  const float* qkv_b  = (const float*)d_in[3];
  const float* out_w  = (const float*)d_in[4];
  const float* out_b  = (const float*)d_in[5];
  const float* table  = (const float*)d_in[6];
  const int*   relidx = (const int*)d_in[7];
  float* out = (float*)d_out;
  char* ws = (char*)d_ws;

  // ws layout (256B-aligned offsets)
  float* bm            = (float*)ws;                       // 14,751,744 B
  unsigned short* wqb  = (unsigned short*)(ws + 14751744); //    221,184 B
  unsigned short* wob  = (unsigned short*)(ws + 14972928); //     73,728 B
  unsigned short* aop  = (unsigned short*)(ws + 15046656); // 19,267,584 B

  static int lds_set = 0;
  (void)lds_set;
  hipFuncSetAttribute((const void*)k_fused,
                      hipFuncAttributeMaxDynamicSharedMemorySize, LDS_TOT);

  k_prep<<<(PREP_TOT + 255) / 256, 256, 0, stream>>>(table, relidx, mask, qkv_w,
                                                     out_w, bm, wqb, wob);
  k_fused<<<BWIN, 448, LDS_TOT, stream>>>(x, wqb, qkv_b, bm, aop);
  k_proj<<<MROWS / 128, 256, 0, stream>>>(aop, wob, out_b, out);
}

// Round 8
// 208.882 us; speedup vs baseline: 1.2873x; 1.2873x over previous
//
#include <hip/hip_runtime.h>

typedef __attribute__((ext_vector_type(8))) __bf16 bf16x8;
typedef __attribute__((ext_vector_type(4))) float f32x4;
typedef __attribute__((ext_vector_type(8))) unsigned short us8;
typedef __attribute__((ext_vector_type(4))) unsigned short us4;

#define NTOK 98
#define CDIM 192
#define NH 6
#define NWIN 64
#define BWIN 512
#define MROWS (BWIN * NTOK)     // 50176
#define NN (NTOK * NTOK)        // 9604
#define SCALE 0.17677669529663687f

#define PREP_BM (NWIN * NH * NN)      // 3687936
#define PREP_WQ (3 * CDIM * CDIM)     // 110592
#define PREP_TOT (PREP_BM + PREP_WQ)  // 3798528

__device__ __forceinline__ unsigned short f2b(float f) {
  unsigned u = __builtin_bit_cast(unsigned, f);
  u += 0x7FFFu + ((u >> 16) & 1u);   // RNE; inputs finite
  return (unsigned short)(u >> 16);
}

__device__ __forceinline__ bf16x8 ldfrag(const unsigned short* p) {
  return __builtin_bit_cast(bf16x8, *(const us8*)p);
}

// ---------------- K0: bm[w][h][ij] = table[relidx[ij]*6+h] + mask[w][ij]  (exact for
// unmasked pairs: mask==0.0); wqb = bf16(qkv_w)
__global__ __launch_bounds__(256) void k_prep(
    const float* __restrict__ table, const int* __restrict__ relidx,
    const float* __restrict__ mask, const float* __restrict__ wq,
    float* __restrict__ bm, unsigned short* __restrict__ wqb) {
  int idx = blockIdx.x * 256 + threadIdx.x;
  if (idx < PREP_BM) {
    int w = idx / (NH * NN);
    int r = idx - w * NH * NN;
    int h = r / NN, ij = r - h * NN;
    bm[idx] = table[relidx[ij] * NH + h] + mask[w * NN + ij];
    return;
  }
  int i2 = idx - PREP_BM;
  if (i2 < PREP_WQ) wqb[i2] = f2b(wq[i2]);
}

// ---------------- K1: qkv = x @ qkv_w^T + qkv_b (q pre-scaled), bf16, PLANE layout:
// qkv[((t*6+head)*MROWS + row)*32 + d]
__global__ __launch_bounds__(256) void k_qkv(
    const float* __restrict__ x, const unsigned short* __restrict__ wqb,
    const float* __restrict__ bias, unsigned short* __restrict__ qkv) {
  __shared__ unsigned short As[128 * 200];
  __shared__ unsigned short Bs[64 * 200];
  const int tid = threadIdx.x;
  const int m0 = blockIdx.x * 128;
  for (int it = 0; it < 24; ++it) {
    int q = it * 256 + tid;
    int row = q / 48, c4 = q - row * 48;
    float4 v = *(const float4*)(x + (m0 + row) * CDIM + c4 * 4);
    us4 u = {f2b(v.x), f2b(v.y), f2b(v.z), f2b(v.w)};
    *(us4*)&As[row * 200 + c4 * 4] = u;
  }
  const int lane = tid & 63;
  const int l15 = lane & 15, hi = lane >> 4;
  const int wr = (tid >> 6) >> 1, wc = (tid >> 6) & 1;
  __syncthreads();
  for (int j = 0; j < 9; ++j) {
    for (int it = 0; it < 6; ++it) {
      int q = it * 256 + tid;
      int row = q / 24, c8 = q - row * 24;
      *(us8*)&Bs[row * 200 + c8 * 8] = *(const us8*)(wqb + (j * 64 + row) * CDIM + c8 * 8);
    }
    __syncthreads();
    f32x4 acc[4][2];
#pragma unroll
    for (int fr = 0; fr < 4; ++fr) { acc[fr][0] = (f32x4)0.f; acc[fr][1] = (f32x4)0.f; }
#pragma unroll
    for (int ks = 0; ks < 6; ++ks) {
      int k0 = ks * 32 + hi * 8;
      bf16x8 b0 = ldfrag(&Bs[(wc * 32 + l15) * 200 + k0]);
      bf16x8 b1 = ldfrag(&Bs[(wc * 32 + 16 + l15) * 200 + k0]);
#pragma unroll
      for (int fr = 0; fr < 4; ++fr) {
        bf16x8 a = ldfrag(&As[(wr * 64 + fr * 16 + l15) * 200 + k0]);
        acc[fr][0] = __builtin_amdgcn_mfma_f32_16x16x32_bf16(a, b0, acc[fr][0], 0, 0, 0);
        acc[fr][1] = __builtin_amdgcn_mfma_f32_16x16x32_bf16(a, b1, acc[fr][1], 0, 0, 0);
      }
    }
    __syncthreads();
#pragma unroll
    for (int fr = 0; fr < 4; ++fr)
#pragma unroll
      for (int fc = 0; fc < 2; ++fc) {
        int colb = j * 64 + wc * 32 + fc * 16;
        int t = (colb >= 2 * CDIM) ? 2 : (colb >= CDIM ? 1 : 0);
        int head = (colb >> 5) - t * NH;
        int d = (colb & 31) + l15;
        long pbase = ((long)(t * NH + head) * MROWS) * 32 + d;
#pragma unroll
        for (int r = 0; r < 4; ++r) {
          int row = m0 + wr * 64 + fr * 16 + hi * 4 + r;
          float v = acc[fr][fc][r] + bias[colb + l15];
          if (t == 0) v *= SCALE;
          qkv[pbase + (long)row * 32] = f2b(v);
        }
      }
  }
}

// ---------------- K2: attention per (b,h). 7 waves; wave wv owns rows [16wv,16wv+16).
// LDS 39.2 KB -> 4 blocks/CU. K and Q read straight from contiguous qkv planes.
__global__ __launch_bounds__(448, 6) void k_attn(
    const unsigned short* __restrict__ qkv, const float* __restrict__ bm,
    unsigned short* __restrict__ ao) {
  __shared__ unsigned short Vt[32 * 136];    // V^T [d][tok], tok>=98 zeroed
  __shared__ unsigned short P[112 * 136];    // probs bf16; cols [112,128) zeroed
  const int tid = threadIdx.x;
  const int h = blockIdx.x % NH;
  const int b = blockIdx.x / NH;
  const int wnd = b & (NWIN - 1);
  const int lane = tid & 63, wv = tid >> 6;
  const int l15 = lane & 15, hi = lane >> 4;
  const long rb = (long)b * NTOK;
  const unsigned short* qp = qkv + ((long)h * MROWS + rb) * 32;
  const unsigned short* kp = qkv + ((long)(NH + h) * MROWS + rb) * 32;
  const unsigned short* vp = qkv + ((long)(2 * NH + h) * MROWS + rb) * 32;
  {
    int row = tid >> 2, q = tid & 3;         // 112 rows x 4 quarters
    if (row < NTOK) {
      us8 vv = *(const us8*)(vp + row * 32 + q * 8);
#pragma unroll
      for (int i = 0; i < 8; ++i) Vt[(q * 8 + i) * 136 + row] = vv[i];
    }
    for (int i = tid; i < 32 * 38; i += 448) {       // zero Vt tok in [98,136)
      int dd = i / 38, n = NTOK + (i - dd * 38);
      Vt[dd * 136 + n] = 0;
    }
    for (int i = tid; i < 112 * 16; i += 448)        // zero P cols [112,128)
      P[(i >> 4) * 136 + 112 + (i & 15)] = 0;
  }
  int qn = wv * 16 + l15;
  us8 qu = (us8)0;
  if (qn < NTOK) qu = *(const us8*)(qp + qn * 32 + hi * 8);
  bf16x8 qf = __builtin_bit_cast(bf16x8, qu);
  __syncthreads();
  // S = (scaled Q) K^T; K fragments straight from global (tail row clamped; garbage
  // sacc for cols>=98 is overridden by the -1e30 select below)
  f32x4 sacc[7];
#pragma unroll
  for (int tc = 0; tc < 7; ++tc) {
    int rowc = tc * 16 + l15;
    rowc = rowc > 97 ? 97 : rowc;
    bf16x8 kb = ldfrag(kp + rowc * 32 + hi * 8);
    sacc[tc] = __builtin_amdgcn_mfma_f32_16x16x32_bf16(qf, kb, (f32x4)0.f, 0, 0, 0);
  }
  const float* bmp = bm + (size_t)(wnd * NH + h) * NN;
  float rsum[4];
#pragma unroll
  for (int r = 0; r < 4; ++r) {
    int row = wv * 16 + hi * 4 + r;
    int rowc = row > 97 ? 97 : row;
    float sv[7];
    float m = -1e30f;
#pragma unroll
    for (int tc = 0; tc < 7; ++tc) {
      int col = tc * 16 + l15;
      int colc = col > 97 ? 97 : col;
      float bmv = bmp[rowc * NTOK + colc];           // unconditional, hoistable
      float val = (col < NTOK && row < NTOK) ? sacc[tc][r] + bmv : -1e30f;
      sv[tc] = val;
      m = fmaxf(m, val);
    }
#pragma unroll
    for (int off = 1; off < 16; off <<= 1) m = fmaxf(m, __shfl_xor(m, off));
    float s = 0.f;
#pragma unroll
    for (int tc = 0; tc < 7; ++tc) {
      float e = __expf(sv[tc] - m);          // cols>=98 -> exp(-inf)=0 exactly
      s += e;
      P[row * 136 + tc * 16 + l15] = f2b(e);
    }
#pragma unroll
    for (int off = 1; off < 16; off <<= 1) s += __shfl_xor(s, off);
    rsum[r] = s;
  }
  // O = P V (own-wave rows; same-wave LDS ops in-order, no barrier needed)
  f32x4 oacc[2];
  oacc[0] = (f32x4)0.f; oacc[1] = (f32x4)0.f;
#pragma unroll
  for (int ks = 0; ks < 4; ++ks) {
    int k0 = ks * 32 + hi * 8;
    bf16x8 pa = ldfrag(&P[(wv * 16 + l15) * 136 + k0]);
#pragma unroll
    for (int tc2 = 0; tc2 < 2; ++tc2) {
      bf16x8 vb = ldfrag(&Vt[(tc2 * 16 + l15) * 136 + k0]);
      oacc[tc2] = __builtin_amdgcn_mfma_f32_16x16x32_bf16(pa, vb, oacc[tc2], 0, 0, 0);
    }
  }
#pragma unroll
  for (int tc2 = 0; tc2 < 2; ++tc2)
#pragma unroll
    for (int r = 0; r < 4; ++r) {
      int row = wv * 16 + hi * 4 + r;
      if (row < NTOK) {
        float v = oacc[tc2][r] / rsum[r];
        ao[(rb + row) * CDIM + h * 32 + tc2 * 16 + l15] = f2b(v);
      }
    }
}

// ---------------- K3: out = ao @ out_w^T + out_b (fp32 weights converted in staging)
__global__ __launch_bounds__(256) void k_proj(
    const unsigned short* __restrict__ a, const float* __restrict__ w,
    const float* __restrict__ bias, float* __restrict__ out) {
  __shared__ unsigned short As[128 * 200];
  __shared__ unsigned short Bs[64 * 200];
  const int tid = threadIdx.x;
  const int m0 = blockIdx.x * 128;
  for (int it = 0; it < 12; ++it) {
    int q = it * 256 + tid;
    int row = q / 24, c8 = q - row * 24;
    *(us8*)&As[row * 200 + c8 * 8] = *(const us8*)(a + (m0 + row) * CDIM + c8 * 8);
  }
  const int lane = tid & 63;
  const int l15 = lane & 15, hi = lane >> 4;
  const int wr = (tid >> 6) >> 1, wc = (tid >> 6) & 1;
  __syncthreads();
  for (int j = 0; j < 3; ++j) {
    for (int it = 0; it < 12; ++it) {
      int q = it * 256 + tid;
      int row = q / 48, c4 = q - row * 48;
      float4 v = *(const float4*)(w + (j * 64 + row) * CDIM + c4 * 4);
      us4 u = {f2b(v.x), f2b(v.y), f2b(v.z), f2b(v.w)};
      *(us4*)&Bs[row * 200 + c4 * 4] = u;
    }
    __syncthreads();
    f32x4 acc[4][2];
#pragma unroll
    for (int fr = 0; fr < 4; ++fr) { acc[fr][0] = (f32x4)0.f; acc[fr][1] = (f32x4)0.f; }
#pragma unroll
    for (int ks = 0; ks < 6; ++ks) {
      int k0 = ks * 32 + hi * 8;
      bf16x8 b0 = ldfrag(&Bs[(wc * 32 + l15) * 200 + k0]);
      bf16x8 b1 = ldfrag(&Bs[(wc * 32 + 16 + l15) * 200 + k0]);
#pragma unroll
      for (int fr = 0; fr < 4; ++fr) {
        bf16x8 aa = ldfrag(&As[(wr * 64 + fr * 16 + l15) * 200 + k0]);
        acc[fr][0] = __builtin_amdgcn_mfma_f32_16x16x32_bf16(aa, b0, acc[fr][0], 0, 0, 0);
        acc[fr][1] = __builtin_amdgcn_mfma_f32_16x16x32_bf16(aa, b1, acc[fr][1], 0, 0, 0);
      }
    }
    __syncthreads();
#pragma unroll
    for (int fr = 0; fr < 4; ++fr)
#pragma unroll
      for (int fc = 0; fc < 2; ++fc)
#pragma unroll
        for (int r = 0; r < 4; ++r) {
          int row = m0 + wr * 64 + fr * 16 + hi * 4 + r;
          int col = j * 64 + wc * 32 + fc * 16 + l15;
          out[row * CDIM + col] = acc[fr][fc][r] + bias[col];
        }
  }
}

extern "C" void kernel_launch(void* const* d_in, const int* in_sizes, int n_in,
                              void* d_out, int out_size, void* d_ws, size_t ws_size,
                              hipStream_t stream) {
  const float* x      = (const float*)d_in[0];
  const float* mask   = (const float*)d_in[1];
  const float* qkv_w  = (const float*)d_in[2];
  const float* qkv_b  = (const float*)d_in[3];
  const float* out_w  = (const float*)d_in[4];
  const float* out_b  = (const float*)d_in[5];
  const float* table  = (const float*)d_in[6];
  const int*   relidx = (const int*)d_in[7];
  float* out = (float*)d_out;
  char* ws = (char*)d_ws;

  // ws layout — peak 91,822,080 B (<= 91,854,080 proven available in round 3).
  // wqb aliases the ao region: written by k_prep, read by k_qkv, dead before
  // k_attn overwrites every byte of ao.
  float* bm            = (float*)ws;                       // 14,751,744 B
  unsigned short* qkvp = (unsigned short*)(ws + 14751744); // 57,802,752 B
  unsigned short* aop  = (unsigned short*)(ws + 72554496); // 19,267,584 B
  unsigned short* wqb  = aop;                              //    221,184 B (alias)

  k_prep<<<PREP_TOT / 256, 256, 0, stream>>>(table, relidx, mask, qkv_w, bm, wqb);
  k_qkv<<<MROWS / 128, 256, 0, stream>>>(x, wqb, qkv_b, qkvp);
  k_attn<<<BWIN * NH, 448, 0, stream>>>(qkvp, bm, aop);
  k_proj<<<MROWS / 128, 256, 0, stream>>>(aop, out_w, out_b, out);
}

// Round 9
// 192.969 us; speedup vs baseline: 1.3935x; 1.0825x over previous
//
#include <hip/hip_runtime.h>

typedef __attribute__((ext_vector_type(8))) __bf16 bf16x8;
typedef __attribute__((ext_vector_type(4))) float f32x4;
typedef __attribute__((ext_vector_type(8))) unsigned short us8;
typedef __attribute__((ext_vector_type(4))) unsigned short us4;

#define NTOK 98
#define CDIM 192
#define NH 6
#define NWIN 64
#define BWIN 512
#define MROWS (BWIN * NTOK)     // 50176
#define NN (NTOK * NTOK)        // 9604
#define SCALE 0.17677669529663687f

#define BMH_SLICE (112 * 128)              // 14336 u16 per (wnd,h)
#define PREP_BMH (NWIN * NH * BMH_SLICE)   // 5,505,024
#define PREP_WQ (3 * CDIM * CDIM)          // 110,592
#define PREP_XB (MROWS * CDIM)             // 9,633,792
#define PREP_TOT (PREP_BMH + PREP_WQ + PREP_XB)  // 15,249,408 = 256*59568

__device__ __forceinline__ unsigned short f2b(float f) {
  unsigned u = __builtin_bit_cast(unsigned, f);
  u += 0x7FFFu + ((u >> 16) & 1u);   // RNE; inputs finite
  return (unsigned short)(u >> 16);
}

__device__ __forceinline__ float b2f(unsigned short u) {
  return __builtin_bit_cast(float, (unsigned)u << 16);
}

__device__ __forceinline__ bf16x8 ldfrag(const unsigned short* p) {
  return __builtin_bit_cast(bf16x8, *(const us8*)p);
}

// ---------------- K0: prep.
// bmh[(wnd*6+h)][row][l15][tc] = bf16(table[relidx]*+mask) for row<98,col=tc*16+l15<98,
//   else 0xFF80 (-inf). wqb = bf16(qkv_w). xb = bf16(x) (bit-identical to old staging).
__global__ __launch_bounds__(256) void k_prep(
    const float* __restrict__ table, const int* __restrict__ relidx,
    const float* __restrict__ mask, const float* __restrict__ wq,
    const float* __restrict__ x, unsigned short* __restrict__ bmh,
    unsigned short* __restrict__ wqb, unsigned short* __restrict__ xb) {
  int idx = blockIdx.x * 256 + threadIdx.x;
  if (idx < PREP_BMH) {
    int slice = idx / BMH_SLICE;
    int rem = idx - slice * BMH_SLICE;
    int row = rem >> 7;
    int li = rem & 127;
    int l = li >> 3, tc = li & 7;
    int col = tc * 16 + l;
    int wnd = slice / NH, h = slice - wnd * NH;
    unsigned short v = 0xFF80;               // bf16 -inf
    if (row < NTOK && col < NTOK && tc < 7) {
      int ij = row * NTOK + col;
      v = f2b(table[relidx[ij] * NH + h] + mask[wnd * NN + ij]);
    }
    bmh[idx] = v;
    return;
  }
  int i2 = idx - PREP_BMH;
  if (i2 < PREP_WQ) { wqb[i2] = f2b(wq[i2]); return; }
  int i3 = i2 - PREP_WQ;
  xb[i3] = f2b(x[i3]);
}

// ---------------- K1: qkv = x @ qkv_w^T + qkv_b (q pre-scaled), bf16, PLANE layout:
// qkv[((t*6+head)*MROWS + row)*32 + d]
__global__ __launch_bounds__(256) void k_qkv(
    const unsigned short* __restrict__ xb, const unsigned short* __restrict__ wqb,
    const float* __restrict__ bias, unsigned short* __restrict__ qkv) {
  __shared__ unsigned short As[128 * 200];
  __shared__ unsigned short Bs[64 * 200];
  const int tid = threadIdx.x;
  const int m0 = blockIdx.x * 128;
  for (int it = 0; it < 12; ++it) {          // 128x192 bf16 us8 copies
    int q = it * 256 + tid;
    int row = q / 24, c8 = q - row * 24;
    *(us8*)&As[row * 200 + c8 * 8] = *(const us8*)(xb + (m0 + row) * CDIM + c8 * 8);
  }
  const int lane = tid & 63;
  const int l15 = lane & 15, hi = lane >> 4;
  const int wr = (tid >> 6) >> 1, wc = (tid >> 6) & 1;
  __syncthreads();
  for (int j = 0; j < 9; ++j) {
    for (int it = 0; it < 6; ++it) {
      int q = it * 256 + tid;
      int row = q / 24, c8 = q - row * 24;
      *(us8*)&Bs[row * 200 + c8 * 8] = *(const us8*)(wqb + (j * 64 + row) * CDIM + c8 * 8);
    }
    __syncthreads();
    f32x4 acc[4][2];
#pragma unroll
    for (int fr = 0; fr < 4; ++fr) { acc[fr][0] = (f32x4)0.f; acc[fr][1] = (f32x4)0.f; }
#pragma unroll
    for (int ks = 0; ks < 6; ++ks) {
      int k0 = ks * 32 + hi * 8;
      bf16x8 b0 = ldfrag(&Bs[(wc * 32 + l15) * 200 + k0]);
      bf16x8 b1 = ldfrag(&Bs[(wc * 32 + 16 + l15) * 200 + k0]);
#pragma unroll
      for (int fr = 0; fr < 4; ++fr) {
        bf16x8 a = ldfrag(&As[(wr * 64 + fr * 16 + l15) * 200 + k0]);
        acc[fr][0] = __builtin_amdgcn_mfma_f32_16x16x32_bf16(a, b0, acc[fr][0], 0, 0, 0);
        acc[fr][1] = __builtin_amdgcn_mfma_f32_16x16x32_bf16(a, b1, acc[fr][1], 0, 0, 0);
      }
    }
    __syncthreads();
#pragma unroll
    for (int fr = 0; fr < 4; ++fr)
#pragma unroll
      for (int fc = 0; fc < 2; ++fc) {
        int colb = j * 64 + wc * 32 + fc * 16;
        int t = (colb >= 2 * CDIM) ? 2 : (colb >= CDIM ? 1 : 0);
        int head = (colb >> 5) - t * NH;
        int d = (colb & 31) + l15;
        long pbase = ((long)(t * NH + head) * MROWS) * 32 + d;
#pragma unroll
        for (int r = 0; r < 4; ++r) {
          int row = m0 + wr * 64 + fr * 16 + hi * 4 + r;
          float v = acc[fr][fc][r] + bias[colb + l15];
          if (t == 0) v *= SCALE;
          qkv[pbase + (long)row * 32] = f2b(v);
        }
      }
  }
}

// ---------------- K2: attention per (b,h). 7 waves; wave wv owns rows [16wv,16wv+16).
// bm pre-fused/padded bf16 (-inf pads): no masks/selects in softmax; bm loads issued
// before the staging barrier. Unclamped K/Q reads stay inside ws; garbage is finite
// and annihilated by the -inf bias rows (NaN confined to discarded output rows).
__global__ __launch_bounds__(448, 6) void k_attn(
    const unsigned short* __restrict__ qkv, const unsigned short* __restrict__ bmh,
    unsigned short* __restrict__ ao) {
  __shared__ unsigned short Vt[32 * 136];    // V^T [d][tok], tok>=98 zeroed
  __shared__ unsigned short P[112 * 136];    // probs bf16; cols [112,128) zeroed
  const int tid = threadIdx.x;
  const int h = blockIdx.x % NH;
  const int b = blockIdx.x / NH;
  const int wnd = b & (NWIN - 1);
  const int lane = tid & 63, wv = tid >> 6;
  const int l15 = lane & 15, hi = lane >> 4;
  const long rb = (long)b * NTOK;
  const unsigned short* qp = qkv + ((long)h * MROWS + rb) * 32;
  const unsigned short* kp = qkv + ((long)(NH + h) * MROWS + rb) * 32;
  const unsigned short* vp = qkv + ((long)(2 * NH + h) * MROWS + rb) * 32;
  const unsigned short* bmp8 = bmh + (size_t)(wnd * NH + h) * BMH_SLICE;
  // early loads: bm fragments + Q (independent of LDS staging)
  us8 bmv[4];
#pragma unroll
  for (int r = 0; r < 4; ++r)
    bmv[r] = *(const us8*)(bmp8 + (wv * 16 + hi * 4 + r) * 128 + l15 * 8);
  bf16x8 qf = ldfrag(qp + (wv * 16 + l15) * 32 + hi * 8);
  {
    int row = tid >> 2, q = tid & 3;         // 112 rows x 4 quarters
    if (row < NTOK) {
      us8 vv = *(const us8*)(vp + row * 32 + q * 8);
#pragma unroll
      for (int i = 0; i < 8; ++i) Vt[(q * 8 + i) * 136 + row] = vv[i];
    }
    for (int i = tid; i < 32 * 38; i += 448) {       // zero Vt tok in [98,136)
      int dd = i / 38, n = NTOK + (i - dd * 38);
      Vt[dd * 136 + n] = 0;
    }
    for (int i = tid; i < 112 * 16; i += 448)        // zero P cols [112,128)
      P[(i >> 4) * 136 + 112 + (i & 15)] = 0;
  }
  __syncthreads();
  // S = (scaled Q) K^T
  f32x4 sacc[7];
#pragma unroll
  for (int tc = 0; tc < 7; ++tc) {
    bf16x8 kb = ldfrag(kp + (tc * 16 + l15) * 32 + hi * 8);
    sacc[tc] = __builtin_amdgcn_mfma_f32_16x16x32_bf16(qf, kb, (f32x4)0.f, 0, 0, 0);
  }
  float rsum[4];
#pragma unroll
  for (int r = 0; r < 4; ++r) {
    int row = wv * 16 + hi * 4 + r;
    float sv[7];
    float m = -1e30f;
#pragma unroll
    for (int tc = 0; tc < 7; ++tc) {
      float val = sacc[tc][r] + b2f(bmv[r][tc]);   // pads are -inf
      sv[tc] = val;
      m = fmaxf(m, val);
    }
#pragma unroll
    for (int off = 1; off < 16; off <<= 1) m = fmaxf(m, __shfl_xor(m, off));
    float s = 0.f;
#pragma unroll
    for (int tc = 0; tc < 7; ++tc) {
      float e = __expf(sv[tc] - m);          // pad cols: exp(-inf)=0 exactly
      s += e;
      P[row * 136 + tc * 16 + l15] = f2b(e);
    }
#pragma unroll
    for (int off = 1; off < 16; off <<= 1) s += __shfl_xor(s, off);
    rsum[r] = s;
  }
  // O = P V (own-wave rows; same-wave LDS ops in-order, no barrier needed)
  f32x4 oacc[2];
  oacc[0] = (f32x4)0.f; oacc[1] = (f32x4)0.f;
#pragma unroll
  for (int ks = 0; ks < 4; ++ks) {
    int k0 = ks * 32 + hi * 8;
    bf16x8 pa = ldfrag(&P[(wv * 16 + l15) * 136 + k0]);
#pragma unroll
    for (int tc2 = 0; tc2 < 2; ++tc2) {
      bf16x8 vb = ldfrag(&Vt[(tc2 * 16 + l15) * 136 + k0]);
      oacc[tc2] = __builtin_amdgcn_mfma_f32_16x16x32_bf16(pa, vb, oacc[tc2], 0, 0, 0);
    }
  }
#pragma unroll
  for (int tc2 = 0; tc2 < 2; ++tc2)
#pragma unroll
    for (int r = 0; r < 4; ++r) {
      int row = wv * 16 + hi * 4 + r;
      if (row < NTOK) {
        float v = oacc[tc2][r] / rsum[r];
        ao[(rb + row) * CDIM + h * 32 + tc2 * 16 + l15] = f2b(v);
      }
    }
}

// ---------------- K3: out = ao @ out_w^T + out_b (fp32 weights converted in staging)
__global__ __launch_bounds__(256) void k_proj(
    const unsigned short* __restrict__ a, const float* __restrict__ w,
    const float* __restrict__ bias, float* __restrict__ out) {
  __shared__ unsigned short As[128 * 200];
  __shared__ unsigned short Bs[64 * 200];
  const int tid = threadIdx.x;
  const int m0 = blockIdx.x * 128;
  for (int it = 0; it < 12; ++it) {
    int q = it * 256 + tid;
    int row = q / 24, c8 = q - row * 24;
    *(us8*)&As[row * 200 + c8 * 8] = *(const us8*)(a + (m0 + row) * CDIM + c8 * 8);
  }
  const int lane = tid & 63;
  const int l15 = lane & 15, hi = lane >> 4;
  const int wr = (tid >> 6) >> 1, wc = (tid >> 6) & 1;
  __syncthreads();
  for (int j = 0; j < 3; ++j) {
    for (int it = 0; it < 12; ++it) {
      int q = it * 256 + tid;
      int row = q / 48, c4 = q - row * 48;
      float4 v = *(const float4*)(w + (j * 64 + row) * CDIM + c4 * 4);
      us4 u = {f2b(v.x), f2b(v.y), f2b(v.z), f2b(v.w)};
      *(us4*)&Bs[row * 200 + c4 * 4] = u;
    }
    __syncthreads();
    f32x4 acc[4][2];
#pragma unroll
    for (int fr = 0; fr < 4; ++fr) { acc[fr][0] = (f32x4)0.f; acc[fr][1] = (f32x4)0.f; }
#pragma unroll
    for (int ks = 0; ks < 6; ++ks) {
      int k0 = ks * 32 + hi * 8;
      bf16x8 b0 = ldfrag(&Bs[(wc * 32 + l15) * 200 + k0]);
      bf16x8 b1 = ldfrag(&Bs[(wc * 32 + 16 + l15) * 200 + k0]);
#pragma unroll
      for (int fr = 0; fr < 4; ++fr) {
        bf16x8 aa = ldfrag(&As[(wr * 64 + fr * 16 + l15) * 200 + k0]);
        acc[fr][0] = __builtin_amdgcn_mfma_f32_16x16x32_bf16(aa, b0, acc[fr][0], 0, 0, 0);
        acc[fr][1] = __builtin_amdgcn_mfma_f32_16x16x32_bf16(aa, b1, acc[fr][1], 0, 0, 0);
      }
    }
    __syncthreads();
#pragma unroll
    for (int fr = 0; fr < 4; ++fr)
#pragma unroll
      for (int fc = 0; fc < 2; ++fc)
#pragma unroll
        for (int r = 0; r < 4; ++r) {
          int row = m0 + wr * 64 + fr * 16 + hi * 4 + r;
          int col = j * 64 + wc * 32 + fc * 16 + l15;
          out[row * CDIM + col] = acc[fr][fc][r] + bias[col];
        }
  }
}

extern "C" void kernel_launch(void* const* d_in, const int* in_sizes, int n_in,
                              void* d_out, int out_size, void* d_ws, size_t ws_size,
                              hipStream_t stream) {
  const float* x      = (const float*)d_in[0];
  const float* mask   = (const float*)d_in[1];
  const float* qkv_w  = (const float*)d_in[2];
  const float* qkv_b  = (const float*)d_in[3];
  const float* out_w  = (const float*)d_in[4];
  const float* out_b  = (const float*)d_in[5];
  const float* table  = (const float*)d_in[6];
  const int*   relidx = (const int*)d_in[7];
  float* out = (float*)d_out;
  char* ws = (char*)d_ws;

  // ws layout — peak 88,301,568 B (< 91.82 MB proven). xb aliases ao: written by
  // k_prep, read by k_qkv, dead before k_attn writes ao.
  unsigned short* bmh  = (unsigned short*)ws;              // 11,010,048 B
  unsigned short* wqb  = (unsigned short*)(ws + 11010048); //    221,184 B
  unsigned short* qkvp = (unsigned short*)(ws + 11231232); // 57,802,752 B
  unsigned short* aop  = (unsigned short*)(ws + 69033984); // 19,267,584 B
  unsigned short* xb   = aop;                              // alias (same size)

  k_prep<<<PREP_TOT / 256, 256, 0, stream>>>(table, relidx, mask, qkv_w, x,
                                             bmh, wqb, xb);
  k_qkv<<<MROWS / 128, 256, 0, stream>>>(xb, wqb, qkv_b, qkvp);
  k_attn<<<BWIN * NH, 448, 0, stream>>>(qkvp, bmh, aop);
  k_proj<<<MROWS / 128, 256, 0, stream>>>(aop, out_w, out_b, out);
}